// Round 5
// baseline (127.410 us; speedup 1.0000x reference)
//
#include <hip/hip_runtime.h>

#define BB 8
#define NN 2048
#define TT 512
#define DD 32
#define SS (NN + TT)     // 2560 total nodes per batch
#define RPB 16           // rows per block (NN % RPB == 0 -> no row-type straddle)
#define RGPB (SS / RPB)  // 160 row-groups per batch
#define NTHR 320         // threads per block; each owns 8 cols (2 vf4)

typedef float vf4 __attribute__((ext_vector_type(4)));

__device__ __forceinline__ float tanh_relu(float x) {
    float t = fmaxf(x, 0.f);
    // tanh(t) = 1 - 2/(exp(2t)+1); exact 0 at t=0; saturates to 1 for large t
    float e = __expf(2.f * t);
    return fmaf(-2.f, __builtin_amdgcn_rcpf(e + 1.f), 1.f);
}

__device__ __forceinline__ float dot32(const vf4* __restrict__ n4,
                                       const vf4* __restrict__ w4) {
    float acc = 0.f;
#pragma unroll
    for (int q = 0; q < DD / 4; ++q) {
        vf4 x = n4[q], w = w4[q];
        acc = fmaf(x.x, w.x, fmaf(x.y, w.y, fmaf(x.z, w.z, fmaf(x.w, w.w, acc))));
    }
    return acc;
}

// Fused: one block per 16-row group. Phase 1: block computes the 2560 col
// scores (+bias) for its row-type into LDS (reads L2-resident node data) and
// the 16 row scores (L/R). Phase 2: each thread writes 16 rows x 8 cols.
__global__ __launch_bounds__(NTHR, 4) void adj_fused(
    const float* __restrict__ sp,   // (B, N, D)
    const float* __restrict__ tp,   // (B, T, D)
    const float* __restrict__ w_ss, const float* __restrict__ b_ss,
    const float* __restrict__ w_tt, const float* __restrict__ b_tt,
    const float* __restrict__ w_st, const float* __restrict__ b_st,
    const float* __restrict__ w_ts, const float* __restrict__ b_ts,
    float* __restrict__ out)
{
    __shared__ vf4 scol4[SS / 4];      // 10240 B: col scores (+bias)
    __shared__ float srow[RPB][2];     // 16 rows x {left,right} score

    int b  = blockIdx.x / RGPB;
    int rg = blockIdx.x - b * RGPB;
    int r0 = rg * RPB;
    bool spatial = (r0 < NN);          // block-uniform

    int tid = threadIdx.x;
    int c0  = tid * 8;                 // first of 8 owned columns
    bool left = (c0 < NN);             // wave-uniform (boundary at tid 256)

    // ---- Phase 1a: col scores -> LDS ----
    const float* wc = (left ? (spatial ? w_ss : w_ts)
                            : (spatial ? w_st : w_tt)) + DD;   // hi half
    float bc = left ? (spatial ? b_ss[0] : b_ts[0])
                    : (spatial ? b_st[0] : b_tt[0]);
    const float* nbase = left ? sp + ((size_t)b * NN + c0) * DD
                              : tp + ((size_t)b * TT + (c0 - NN)) * DD;
    const vf4* w4 = (const vf4*)wc;

    float a[8];
#pragma unroll
    for (int k = 0; k < 8; ++k)
        a[k] = dot32((const vf4*)(nbase + k * DD), w4) + bc;
    scol4[2 * tid]     = (vf4){a[0], a[1], a[2], a[3]};
    scol4[2 * tid + 1] = (vf4){a[4], a[5], a[6], a[7]};

    // ---- Phase 1b: row scores (32 threads, one dot each) ----
    if (tid < 2 * RPB) {
        int rr = tid >> 1, side = tid & 1;
        int r = r0 + rr;
        const float* nv = spatial ? sp + ((size_t)b * NN + r) * DD
                                  : tp + ((size_t)b * TT + (r - NN)) * DD;
        const float* wr_ = (side == 0) ? (spatial ? w_ss : w_ts)
                                       : (spatial ? w_st : w_tt);  // lo half
        srow[rr][side] = dot32((const vf4*)nv, (const vf4*)wr_);
    }
    __syncthreads();

    // ---- Phase 2: write 16 rows ----
    vf4 cv0 = scol4[2 * tid];
    vf4 cv1 = scol4[2 * tid + 1];
    int side = left ? 0 : 1;
    size_t rowbase = (size_t)(b * SS + r0) * SS;

#pragma unroll 4
    for (int r = 0; r < RPB; ++r) {
        float rv = srow[r][side];      // wave-uniform LDS broadcast
        vf4 o0, o1;
        o0.x = tanh_relu(rv + cv0.x); o0.y = tanh_relu(rv + cv0.y);
        o0.z = tanh_relu(rv + cv0.z); o0.w = tanh_relu(rv + cv0.w);
        o1.x = tanh_relu(rv + cv1.x); o1.y = tanh_relu(rv + cv1.y);
        o1.z = tanh_relu(rv + cv1.z); o1.w = tanh_relu(rv + cv1.w);
        vf4* p = (vf4*)(out + rowbase + (size_t)r * SS) + 2 * tid;
        p[0] = o0;
        p[1] = o1;
    }
}

extern "C" void kernel_launch(void* const* d_in, const int* in_sizes, int n_in,
                              void* d_out, int out_size, void* d_ws, size_t ws_size,
                              hipStream_t stream) {
    const float* sp   = (const float*)d_in[0];
    const float* tp   = (const float*)d_in[1];
    const float* w_ss = (const float*)d_in[2];
    const float* b_ss = (const float*)d_in[3];
    const float* w_tt = (const float*)d_in[4];
    const float* b_tt = (const float*)d_in[5];
    const float* w_st = (const float*)d_in[6];
    const float* b_st = (const float*)d_in[7];
    const float* w_ts = (const float*)d_in[8];
    const float* b_ts = (const float*)d_in[9];
    float* out = (float*)d_out;

    adj_fused<<<BB * RGPB, NTHR, 0, stream>>>(
        sp, tp, w_ss, b_ss, w_tt, b_tt, w_st, b_st, w_ts, b_ts, out);
}

// Round 6
// 40.260 us; speedup vs baseline: 3.1647x; 3.1647x over previous
//
#include <hip/hip_runtime.h>

#define BB 8
#define NN 2048
#define TT 512
#define DD 32
#define SS (NN + TT)   // 2560 total nodes per batch
#define RPB 4          // rows per block (N % RPB == 0 -> no region straddle)

typedef float vf4 __attribute__((ext_vector_type(4)));

// ws layout (floats): rowL[B*SS] | rowR[B*SS] | colS[B*SS] | colT[B*SS]

// 320 blocks x 64 threads: one node per thread, one wave per block, all CUs
// engaged. Branch (spatial vs temporal) is block-uniform since NN % 64 == 0.
__global__ __launch_bounds__(64) void precompute_scores(
    const float* __restrict__ sp,   // (B, N, D)
    const float* __restrict__ tp,   // (B, T, D)
    const float* __restrict__ w_ss, const float* __restrict__ b_ss,
    const float* __restrict__ w_tt, const float* __restrict__ b_tt,
    const float* __restrict__ w_st, const float* __restrict__ b_st,
    const float* __restrict__ w_ts, const float* __restrict__ b_ts,
    float* __restrict__ ws)
{
    int idx = blockIdx.x * 64 + threadIdx.x;  // b*SS + i, < 20480
    int b = idx / SS;
    int i = idx - b * SS;

    const float *v, *wl, *wr, *wcs, *wct;
    float bs, bt;
    if (i < NN) {
        v   = sp + ((size_t)b * NN + i) * DD;
        wl  = w_ss;       wr  = w_st;
        wcs = w_ss + DD;  wct = w_ts + DD;
        bs  = b_ss[0];    bt  = b_ts[0];
    } else {
        v   = tp + ((size_t)b * TT + (i - NN)) * DD;
        wl  = w_ts;       wr  = w_tt;
        wcs = w_st + DD;  wct = w_tt + DD;
        bs  = b_st[0];    bt  = b_tt[0];
    }

    const vf4* v4   = (const vf4*)v;
    const vf4* wl4  = (const vf4*)wl;
    const vf4* wr4  = (const vf4*)wr;
    const vf4* wcs4 = (const vf4*)wcs;
    const vf4* wct4 = (const vf4*)wct;

    float aL = 0.f, aR = 0.f, aS = 0.f, aT = 0.f;
#pragma unroll
    for (int q = 0; q < DD / 4; ++q) {
        vf4 x = v4[q];
        vf4 a = wl4[q], c = wr4[q], s = wcs4[q], t = wct4[q];
        aL = fmaf(x.x, a.x, fmaf(x.y, a.y, fmaf(x.z, a.z, fmaf(x.w, a.w, aL))));
        aR = fmaf(x.x, c.x, fmaf(x.y, c.y, fmaf(x.z, c.z, fmaf(x.w, c.w, aR))));
        aS = fmaf(x.x, s.x, fmaf(x.y, s.y, fmaf(x.z, s.z, fmaf(x.w, s.w, aS))));
        aT = fmaf(x.x, t.x, fmaf(x.y, t.y, fmaf(x.z, t.z, fmaf(x.w, t.w, aT))));
    }

    float* rowL = ws;
    float* rowR = ws + 1 * BB * SS;
    float* colS = ws + 2 * BB * SS;
    float* colT = ws + 3 * BB * SS;
    rowL[idx] = aL;
    rowR[idx] = aR;
    colS[idx] = aS + bs;
    colT[idx] = aT + bt;
}

__device__ __forceinline__ float tanh_relu(float x) {
    float t = fmaxf(x, 0.f);
    // tanh(t) = 1 - 2/(exp(2t)+1); exact 0 at t=0
    float e = __expf(2.f * t);
    return fmaf(-2.f, __builtin_amdgcn_rcpf(e + 1.f), 1.f);
}

// One block per 4-row group (b, r0..r0+3); 640 threads, each thread:
// load col float4 once, write 4 rows' float4 (plain stores; NT regressed).
__global__ __launch_bounds__(640) void adj_kernel(
    const float* __restrict__ ws, float* __restrict__ out)
{
    const int RGPB = SS / RPB;     // row-groups per batch = 640
    int gid = blockIdx.x;          // b*RGPB + rg
    int b  = gid / RGPB;
    int rg = gid - b * RGPB;
    int r0 = rg * RPB;

    const float* rowL = ws;
    const float* rowR = ws + 1 * BB * SS;
    const float* colS = ws + 2 * BB * SS;
    const float* colT = ws + 3 * BB * SS;

    int base = b * SS + r0;        // index of first row's score / output row

    int c4 = threadIdx.x;          // 0..639, 4 columns each
    const float* col = ((r0 < NN) ? colS : colT) + (size_t)b * SS;
    vf4 cv = ((const vf4*)col)[c4];

    bool left = (c4 < NN / 4);     // uniform per wave

    float rv0 = left ? rowL[base + 0] : rowR[base + 0];
    float rv1 = left ? rowL[base + 1] : rowR[base + 1];
    float rv2 = left ? rowL[base + 2] : rowR[base + 2];
    float rv3 = left ? rowL[base + 3] : rowR[base + 3];

    vf4* o0 = (vf4*)(out + (size_t)(base + 0) * SS) + c4;
    vf4* o1 = (vf4*)(out + (size_t)(base + 1) * SS) + c4;
    vf4* o2 = (vf4*)(out + (size_t)(base + 2) * SS) + c4;
    vf4* o3 = (vf4*)(out + (size_t)(base + 3) * SS) + c4;

    vf4 v0, v1, v2, v3;
    v0.x = tanh_relu(rv0 + cv.x); v0.y = tanh_relu(rv0 + cv.y);
    v0.z = tanh_relu(rv0 + cv.z); v0.w = tanh_relu(rv0 + cv.w);
    v1.x = tanh_relu(rv1 + cv.x); v1.y = tanh_relu(rv1 + cv.y);
    v1.z = tanh_relu(rv1 + cv.z); v1.w = tanh_relu(rv1 + cv.w);
    v2.x = tanh_relu(rv2 + cv.x); v2.y = tanh_relu(rv2 + cv.y);
    v2.z = tanh_relu(rv2 + cv.z); v2.w = tanh_relu(rv2 + cv.w);
    v3.x = tanh_relu(rv3 + cv.x); v3.y = tanh_relu(rv3 + cv.y);
    v3.z = tanh_relu(rv3 + cv.z); v3.w = tanh_relu(rv3 + cv.w);

    *o0 = v0; *o1 = v1; *o2 = v2; *o3 = v3;
}

extern "C" void kernel_launch(void* const* d_in, const int* in_sizes, int n_in,
                              void* d_out, int out_size, void* d_ws, size_t ws_size,
                              hipStream_t stream) {
    const float* sp   = (const float*)d_in[0];
    const float* tp   = (const float*)d_in[1];
    const float* w_ss = (const float*)d_in[2];
    const float* b_ss = (const float*)d_in[3];
    const float* w_tt = (const float*)d_in[4];
    const float* b_tt = (const float*)d_in[5];
    const float* w_st = (const float*)d_in[6];
    const float* b_st = (const float*)d_in[7];
    const float* w_ts = (const float*)d_in[8];
    const float* b_ts = (const float*)d_in[9];
    float* out = (float*)d_out;
    float* ws  = (float*)d_ws;   // needs 4*B*SS*4 = 320 KB

    precompute_scores<<<(BB * SS) / 64, 64, 0, stream>>>(
        sp, tp, w_ss, b_ss, w_tt, b_tt, w_st, b_st, w_ts, b_ts, ws);

    adj_kernel<<<(BB * SS) / RPB, 640, 0, stream>>>(ws, out);
}

// Round 8
// 40.223 us; speedup vs baseline: 3.1676x; 1.0009x over previous
//
#include <hip/hip_runtime.h>

#define BB 8
#define NN 2048
#define TT 512
#define DD 32
#define SS (NN + TT)   // 2560 total nodes per batch
#define RPB 4          // rows per block (N % RPB == 0 -> no region straddle)

typedef float vf4 __attribute__((ext_vector_type(4)));

// ws layout (floats): rowL[B*SS] | rowR[B*SS] | colS[B*SS] | colT[B*SS]

// 320 blocks x 64 threads: one node per thread, one wave per block, all CUs
// engaged. Branch (spatial vs temporal) is block-uniform since NN % 64 == 0.
__global__ __launch_bounds__(64) void precompute_scores(
    const float* __restrict__ sp,   // (B, N, D)
    const float* __restrict__ tp,   // (B, T, D)
    const float* __restrict__ w_ss, const float* __restrict__ b_ss,
    const float* __restrict__ w_tt, const float* __restrict__ b_tt,
    const float* __restrict__ w_st, const float* __restrict__ b_st,
    const float* __restrict__ w_ts, const float* __restrict__ b_ts,
    float* __restrict__ ws)
{
    int idx = blockIdx.x * 64 + threadIdx.x;  // b*SS + i, < 20480
    int b = idx / SS;
    int i = idx - b * SS;

    const float *v, *wl, *wr, *wcs, *wct;
    float bs, bt;
    if (i < NN) {
        v   = sp + ((size_t)b * NN + i) * DD;
        wl  = w_ss;       wr  = w_st;
        wcs = w_ss + DD;  wct = w_ts + DD;
        bs  = b_ss[0];    bt  = b_ts[0];
    } else {
        v   = tp + ((size_t)b * TT + (i - NN)) * DD;
        wl  = w_ts;       wr  = w_tt;
        wcs = w_st + DD;  wct = w_tt + DD;
        bs  = b_st[0];    bt  = b_tt[0];
    }

    const vf4* v4   = (const vf4*)v;
    const vf4* wl4  = (const vf4*)wl;
    const vf4* wr4  = (const vf4*)wr;
    const vf4* wcs4 = (const vf4*)wcs;
    const vf4* wct4 = (const vf4*)wct;

    float aL = 0.f, aR = 0.f, aS = 0.f, aT = 0.f;
#pragma unroll
    for (int q = 0; q < DD / 4; ++q) {
        vf4 x = v4[q];
        vf4 a = wl4[q], c = wr4[q], s = wcs4[q], t = wct4[q];
        aL = fmaf(x.x, a.x, fmaf(x.y, a.y, fmaf(x.z, a.z, fmaf(x.w, a.w, aL))));
        aR = fmaf(x.x, c.x, fmaf(x.y, c.y, fmaf(x.z, c.z, fmaf(x.w, c.w, aR))));
        aS = fmaf(x.x, s.x, fmaf(x.y, s.y, fmaf(x.z, s.z, fmaf(x.w, s.w, aS))));
        aT = fmaf(x.x, t.x, fmaf(x.y, t.y, fmaf(x.z, t.z, fmaf(x.w, t.w, aT))));
    }

    float* rowL = ws;
    float* rowR = ws + 1 * BB * SS;
    float* colS = ws + 2 * BB * SS;
    float* colT = ws + 3 * BB * SS;
    rowL[idx] = aL;
    rowR[idx] = aR;
    colS[idx] = aS + bs;
    colT[idx] = aT + bt;
}

__device__ __forceinline__ float tanh_relu(float x) {
    float t = fmaxf(x, 0.f);
    // tanh(t) = 1 - 2/(exp(2t)+1); exact 0 at t=0
    float e = __expf(2.f * t);
    return fmaf(-2.f, __builtin_amdgcn_rcpf(e + 1.f), 1.f);
}

// One block per 4-row group (b, r0..r0+3); 640 threads, each thread:
// load col float4 once, write 4 rows' float4 (plain stores; NT regressed).
__global__ __launch_bounds__(640) void adj_kernel(
    const float* __restrict__ ws, float* __restrict__ out)
{
    const int RGPB = SS / RPB;     // row-groups per batch = 640
    int gid = blockIdx.x;          // b*RGPB + rg
    int b  = gid / RGPB;
    int rg = gid - b * RGPB;
    int r0 = rg * RPB;

    const float* rowL = ws;
    const float* rowR = ws + 1 * BB * SS;
    const float* colS = ws + 2 * BB * SS;
    const float* colT = ws + 3 * BB * SS;

    int base = b * SS + r0;        // index of first row's score / output row

    int c4 = threadIdx.x;          // 0..639, 4 columns each
    const float* col = ((r0 < NN) ? colS : colT) + (size_t)b * SS;
    vf4 cv = ((const vf4*)col)[c4];

    bool left = (c4 < NN / 4);     // uniform per wave

    float rv0 = left ? rowL[base + 0] : rowR[base + 0];
    float rv1 = left ? rowL[base + 1] : rowR[base + 1];
    float rv2 = left ? rowL[base + 2] : rowR[base + 2];
    float rv3 = left ? rowL[base + 3] : rowR[base + 3];

    vf4* o0 = (vf4*)(out + (size_t)(base + 0) * SS) + c4;
    vf4* o1 = (vf4*)(out + (size_t)(base + 1) * SS) + c4;
    vf4* o2 = (vf4*)(out + (size_t)(base + 2) * SS) + c4;
    vf4* o3 = (vf4*)(out + (size_t)(base + 3) * SS) + c4;

    vf4 v0, v1, v2, v3;
    v0.x = tanh_relu(rv0 + cv.x); v0.y = tanh_relu(rv0 + cv.y);
    v0.z = tanh_relu(rv0 + cv.z); v0.w = tanh_relu(rv0 + cv.w);
    v1.x = tanh_relu(rv1 + cv.x); v1.y = tanh_relu(rv1 + cv.y);
    v1.z = tanh_relu(rv1 + cv.z); v1.w = tanh_relu(rv1 + cv.w);
    v2.x = tanh_relu(rv2 + cv.x); v2.y = tanh_relu(rv2 + cv.y);
    v2.z = tanh_relu(rv2 + cv.z); v2.w = tanh_relu(rv2 + cv.w);
    v3.x = tanh_relu(rv3 + cv.x); v3.y = tanh_relu(rv3 + cv.y);
    v3.z = tanh_relu(rv3 + cv.z); v3.w = tanh_relu(rv3 + cv.w);

    *o0 = v0; *o1 = v1; *o2 = v2; *o3 = v3;
}

extern "C" void kernel_launch(void* const* d_in, const int* in_sizes, int n_in,
                              void* d_out, int out_size, void* d_ws, size_t ws_size,
                              hipStream_t stream) {
    const float* sp   = (const float*)d_in[0];
    const float* tp   = (const float*)d_in[1];
    const float* w_ss = (const float*)d_in[2];
    const float* b_ss = (const float*)d_in[3];
    const float* w_tt = (const float*)d_in[4];
    const float* b_tt = (const float*)d_in[5];
    const float* w_st = (const float*)d_in[6];
    const float* b_st = (const float*)d_in[7];
    const float* w_ts = (const float*)d_in[8];
    const float* b_ts = (const float*)d_in[9];
    float* out = (float*)d_out;
    float* ws  = (float*)d_ws;   // needs 4*B*SS*4 = 320 KB

    precompute_scores<<<(BB * SS) / 64, 64, 0, stream>>>(
        sp, tp, w_ss, b_ss, w_tt, b_tt, w_st, b_st, w_ts, b_ts, ws);

    adj_kernel<<<(BB * SS) / RPB, 640, 0, stream>>>(ws, out);
}